// Round 13
// baseline (248.600 us; speedup 1.0000x reference)
//
#include <hip/hip_runtime.h>
#include <hip/hip_bf16.h>

#define D_MODEL 1024
#define NHEADS  16
#define DH      64
#define SEQ     2048
#define BATCH   2

#define LOG2E 1.4426950408889634f
#define MASKB2 (-1e-6f * LOG2E)   // mask value in exp2 domain
#define DEFER_THR 11.5456f        // 8 * log2e
#define NEG_INF (-__builtin_inff())

typedef __attribute__((ext_vector_type(8))) short short8;
typedef __attribute__((ext_vector_type(4))) short short4v;
typedef __attribute__((ext_vector_type(4))) float f32x4;

#define AS1C(p) ((const __attribute__((address_space(1))) void*)(p))
#define AS3(p)  ((__attribute__((address_space(3))) void*)(p))

union PB  { short4v s4; unsigned int u[2]; };
union PW8 { short8  s8; unsigned int u[4]; };

static __device__ __forceinline__ float fexp2(float x) {
    return __builtin_amdgcn_exp2f(x);   // v_exp_f32
}

static __device__ __forceinline__ unsigned int pk2(float lo, float hi) {
    __hip_bfloat16 a = __float2bfloat16(lo), b = __float2bfloat16(hi);
    unsigned short au = *(unsigned short*)&a, bu = *(unsigned short*)&b;
    return (unsigned int)au | ((unsigned int)bu << 16);
}

// ---------------- fold bilinear W into Wq (+log2e), R4 access pattern ----------------
__global__ __launch_bounds__(256) void fold_kernel(const float* __restrict__ Wq,
                                                   const float* __restrict__ bq,
                                                   const float* __restrict__ W,
                                                   float* __restrict__ Wq2,
                                                   float* __restrict__ bq2) {
    if (blockIdx.x < 4096) {
        int idx = blockIdx.x * 256 + threadIdx.x;   // over D*D
        int row = idx >> 10;                        // block-uniform
        int col = idx & 1023;
        int h = col >> 6, j = col & 63;
        const float* wqr = Wq + (size_t)row * D_MODEL + h * DH;
        float s = 0.f;
#pragma unroll
        for (int d = 0; d < DH; ++d) s += wqr[d] * W[d * DH + j];
        Wq2[idx] = s * LOG2E;
    } else {
        int col = (blockIdx.x - 4096) * 256 + threadIdx.x;
        int h = col >> 6, j = col & 63;
        float s = 0.f;
#pragma unroll
        for (int d = 0; d < DH; ++d) s += bq[h * DH + d] * W[d * DH + j];
        bq2[col] = s * LOG2E;
    }
}

// ---------------- transpose+convert 4 weight matrices in one launch ----------------
__global__ __launch_bounds__(256) void transpose4_kernel(const float* __restrict__ W0,
                                                         const float* __restrict__ W1,
                                                         const float* __restrict__ W2,
                                                         const float* __restrict__ W3,
                                                         __hip_bfloat16* __restrict__ T0,
                                                         __hip_bfloat16* __restrict__ T1,
                                                         __hip_bfloat16* __restrict__ T2,
                                                         __hip_bfloat16* __restrict__ T3) {
    __shared__ float sT[32][33];
    int z = blockIdx.z;
    const float* Win = (z == 0) ? W0 : (z == 1) ? W1 : (z == 2) ? W2 : W3;
    __hip_bfloat16* Wt = (z == 0) ? T0 : (z == 1) ? T1 : (z == 2) ? T2 : T3;
    int n0 = blockIdx.x * 32, k0 = blockIdx.y * 32;
    int tx = threadIdx.x & 31, ty = threadIdx.x >> 5;  // ty 0..7
#pragma unroll
    for (int i = 0; i < 4; ++i)
        sT[ty + i * 8][tx] = Win[(size_t)(k0 + ty + i * 8) * D_MODEL + n0 + tx];
    __syncthreads();
#pragma unroll
    for (int i = 0; i < 4; ++i)
        Wt[(size_t)(n0 + ty + i * 8) * D_MODEL + k0 + tx] = __float2bfloat16(sT[tx][ty + i * 8]);
}

// ========== GEMM core, A in fp32 (fused convert), 128x128 tile, BK=32, 2-phase ==========
// A tile staged as f32 (16KB/buf) with T2 XOR-swizzle: linear LDS dest, inverse-swizzled
// global source (rule 21), swizzled ds_read (slot ^ (row&7); row&7 == li&7, m-invariant).
#define GEMM_CORE_F32A(A_, BT_)                                                             \
    __shared__ float sAf[2][128 * 32];                                                      \
    __shared__ __hip_bfloat16 sB[2][128 * 32];                                              \
    const int t = threadIdx.x;                                                              \
    const int lane = t & 63, w = t >> 6;                                                    \
    const int g = lane >> 4, li = lane & 15;                                                \
    const int r0 = blockIdx.y * 128, c0 = blockIdx.x * 128;                                 \
    const int wr = (w >> 1) * 64, wc = (w & 1) * 64;                                        \
    f32x4 acc[4][4] = {};                                                                   \
    auto stage = [&](int bb, int k0) {                                                      \
        _Pragma("unroll")                                                                   \
        for (int i = 0; i < 4; ++i) {                                                       \
            int o = (i * 4 + w) * 1024 + lane * 16;   /* byte in 16KB f32 tile */           \
            int row = o >> 7;                         /* 128B rows */                       \
            int slot = (o & 127) >> 4;                                                      \
            int sslot = slot ^ (row & 7);             /* inverse swizzle on source */       \
            __builtin_amdgcn_global_load_lds(                                               \
                AS1C(A_ + (size_t)(r0 + row) * 1024 + k0 + sslot * 4),                      \
                AS3((char*)sAf[bb] + (i * 4 + w) * 1024), 16, 0, 0);                        \
        }                                                                                   \
        _Pragma("unroll")                                                                   \
        for (int i = 0; i < 2; ++i) {                                                       \
            int o = (i * 4 + w) * 1024 + lane * 16;                                         \
            int row = o >> 6, ce = (o & 63) >> 1;                                           \
            __builtin_amdgcn_global_load_lds(AS1C(BT_ + (size_t)(c0 + row) * 1024 + k0 + ce),\
                                             AS3((char*)sB[bb] + (i * 4 + w) * 1024), 16, 0, 0); \
        }                                                                                   \
    };                                                                                      \
    stage(0, 0);                                                                            \
    asm volatile("s_waitcnt vmcnt(0)" ::: "memory");                                        \
    __syncthreads();                                                                        \
    const int xr0 = (((2 * g)     ^ (li & 7)) << 4);                                        \
    const int xr1 = (((2 * g + 1) ^ (li & 7)) << 4);                                        \
    int cur = 0;                                                                            \
    for (int k0 = 0; k0 < 1024; k0 += 32) {                                                 \
        if (k0 + 32 < 1024) stage(cur ^ 1, k0 + 32);                                        \
        short8 af[4], bf[4];                                                                \
        _Pragma("unroll")                                                                   \
        for (int m = 0; m < 4; ++m) {                                                       \
            const char* base = (const char*)sAf[cur] + (wr + m * 16 + li) * 128;            \
            f32x4 a0 = *(const f32x4*)(base + xr0);                                         \
            f32x4 a1 = *(const f32x4*)(base + xr1);                                         \
            PW8 uu;                                                                         \
            uu.u[0] = pk2(a0[0], a0[1]); uu.u[1] = pk2(a0[2], a0[3]);                       \
            uu.u[2] = pk2(a1[0], a1[1]); uu.u[3] = pk2(a1[2], a1[3]);                       \
            af[m] = uu.s8;                                                                  \
        }                                                                                   \
        _Pragma("unroll")                                                                   \
        for (int n = 0; n < 4; ++n)                                                         \
            bf[n] = *(const short8*)(sB[cur] + (wc + n * 16 + li) * 32 + g * 8);            \
        _Pragma("unroll")                                                                   \
        for (int m = 0; m < 4; ++m)                                                         \
            _Pragma("unroll")                                                               \
            for (int n = 0; n < 4; ++n)                                                     \
                acc[m][n] = __builtin_amdgcn_mfma_f32_16x16x32_bf16(af[m], bf[n], acc[m][n], 0, 0, 0); \
        asm volatile("s_waitcnt vmcnt(0)" ::: "memory");                                    \
        __syncthreads();                                                                    \
        cur ^= 1;                                                                           \
    }

// ================= GEMM core bf16-A (128x128 tile) — for out-projection =================
#define GEMM_CORE(A_, BT_)                                                                  \
    __shared__ __hip_bfloat16 sA[2][128 * 32];                                              \
    __shared__ __hip_bfloat16 sB[2][128 * 32];                                              \
    const int t = threadIdx.x;                                                              \
    const int lane = t & 63, w = t >> 6;                                                    \
    const int g = lane >> 4, li = lane & 15;                                                \
    const int r0 = blockIdx.y * 128, c0 = blockIdx.x * 128;                                 \
    const int wr = (w >> 1) * 64, wc = (w & 1) * 64;                                        \
    f32x4 acc[4][4] = {};                                                                   \
    auto stage = [&](int bb, int k0) {                                                      \
        _Pragma("unroll")                                                                   \
        for (int i = 0; i < 2; ++i) {                                                       \
            int o = (i * 4 + w) * 1024 + lane * 16;                                         \
            int row = o >> 6, ce = (o & 63) >> 1;                                           \
            __builtin_amdgcn_global_load_lds(AS1C(A_ + (size_t)(r0 + row) * 1024 + k0 + ce),\
                                             AS3((char*)sA[bb] + (i * 4 + w) * 1024), 16, 0, 0); \
            __builtin_amdgcn_global_load_lds(AS1C(BT_ + (size_t)(c0 + row) * 1024 + k0 + ce),\
                                             AS3((char*)sB[bb] + (i * 4 + w) * 1024), 16, 0, 0); \
        }                                                                                   \
    };                                                                                      \
    stage(0, 0);                                                                            \
    asm volatile("s_waitcnt vmcnt(0)" ::: "memory");                                        \
    __syncthreads();                                                                        \
    int cur = 0;                                                                            \
    for (int k0 = 0; k0 < 1024; k0 += 32) {                                                 \
        if (k0 + 32 < 1024) stage(cur ^ 1, k0 + 32);                                        \
        short8 af[4], bf[4];                                                                \
        _Pragma("unroll")                                                                   \
        for (int m = 0; m < 4; ++m)                                                         \
            af[m] = *(const short8*)(sA[cur] + (wr + m * 16 + li) * 32 + g * 8);            \
        _Pragma("unroll")                                                                   \
        for (int n = 0; n < 4; ++n)                                                         \
            bf[n] = *(const short8*)(sB[cur] + (wc + n * 16 + li) * 32 + g * 8);            \
        _Pragma("unroll")                                                                   \
        for (int m = 0; m < 4; ++m)                                                         \
            _Pragma("unroll")                                                               \
            for (int n = 0; n < 4; ++n)                                                     \
                acc[m][n] = __builtin_amdgcn_mfma_f32_16x16x32_bf16(af[m], bf[n], acc[m][n], 0, 0, 0); \
        asm volatile("s_waitcnt vmcnt(0)" ::: "memory");                                    \
        __syncthreads();                                                                    \
        cur ^= 1;                                                                           \
    }

// ---------------- QKV projections from RAW f32 inputs (fused convert), one launch ---------
// z=0: queries -> Qp [B*H][S][DH];  z=1: keys -> Kp same;  z=2: values -> Vt [B*H][DH][S]
__global__ __launch_bounds__(256) void gemm_qkv_kernel(
    const float* __restrict__ Xq, const float* __restrict__ Xk, const float* __restrict__ Xv,
    const __hip_bfloat16* __restrict__ WqT, const __hip_bfloat16* __restrict__ WkT,
    const __hip_bfloat16* __restrict__ WvT,
    const float* __restrict__ bq2, const float* __restrict__ bk, const float* __restrict__ bv,
    __hip_bfloat16* __restrict__ Qp, __hip_bfloat16* __restrict__ Kp,
    __hip_bfloat16* __restrict__ Vt) {
    const int z = blockIdx.z;
    const float* A           = (z == 0) ? Xq  : (z == 1) ? Xk  : Xv;
    const __hip_bfloat16* BT = (z == 0) ? WqT : (z == 1) ? WkT : WvT;
    const float* bias        = (z == 0) ? bq2 : (z == 1) ? bk  : bv;
    __hip_bfloat16* C        = (z == 0) ? Qp  : (z == 1) ? Kp  : Vt;

    GEMM_CORE_F32A(A, BT)

#pragma unroll
    for (int m = 0; m < 4; ++m) {
#pragma unroll
        for (int n = 0; n < 4; ++n) {
            int col = c0 + wc + n * 16 + li;
            float bs = bias[col];
            int row0 = r0 + wr + m * 16 + g * 4;
            int h = col >> 6, d = col & 63;
            if (z == 2) {
                int b = row0 >> 11, s0 = row0 & 2047;
                __hip_bfloat16 o4[4];
#pragma unroll
                for (int r = 0; r < 4; ++r) o4[r] = __float2bfloat16(acc[m][n][r] + bs);
                *(short4*)(C + (((size_t)(b * NHEADS + h)) * DH + d) * SEQ + s0) = *(short4*)o4;
            } else {
#pragma unroll
                for (int r = 0; r < 4; ++r) {
                    int row = row0 + r;
                    int b = row >> 11, s = row & 2047;
                    C[(((size_t)(b * NHEADS + h)) * SEQ + s) * DH + d] =
                        __float2bfloat16(acc[m][n][r] + bs);
                }
            }
        }
    }
}

// ---------------- output projection (fp32 out) ----------------
__global__ __launch_bounds__(256) void gemm_out_kernel(
    const __hip_bfloat16* __restrict__ A, const __hip_bfloat16* __restrict__ BT,
    const float* __restrict__ bias, float* __restrict__ C) {
    GEMM_CORE(A, BT)
#pragma unroll
    for (int m = 0; m < 4; ++m) {
#pragma unroll
        for (int n = 0; n < 4; ++n) {
            int col = c0 + wc + n * 16 + li;
            float bs = bias[col];
            int row0 = r0 + wr + m * 16 + g * 4;
#pragma unroll
            for (int r = 0; r < 4; ++r)
                C[(size_t)(row0 + r) * D_MODEL + col] = acc[m][n][r] + bs;
        }
    }
}

// ---------------- Vsum[bh][dh] = sum_{s >= loop_end_b} Vt[bh][dh][s]  (f32) ----------------
__global__ __launch_bounds__(256) void vsum_kernel(const __hip_bfloat16* __restrict__ Vt,
                                                   const int* __restrict__ thresholds,
                                                   float* __restrict__ Vsum) {
    int bh = blockIdx.x, b = bh >> 4;
    int thresh = thresholds[b];
    int loop_end = min(SEQ, ((thresh + 63) >> 6) << 6);
    int t = threadIdx.x;
    int dh = t >> 2, sub = t & 3;
    const __hip_bfloat16* row = Vt + ((size_t)bh * DH + dh) * SEQ;
    float s = 0.f;
    for (int s0 = loop_end + sub * 8; s0 < SEQ; s0 += 32) {
        short8 v = *(const short8*)(row + s0);
#pragma unroll
        for (int j = 0; j < 8; ++j) {
            unsigned short us = (unsigned short)v[j];
            s += __bfloat162float(*(__hip_bfloat16*)&us);
        }
    }
    s += __shfl_xor(s, 1);
    s += __shfl_xor(s, 2);
    if (sub == 0) Vsum[bh * DH + dh] = s;
}

// ------- flash MFMA attention: T15 double-pipeline (QK(t) || SM+PV(t-1)), 2-buffer -------
// Qp/Kp: [B*H][S][DH] bf16 (Q pre-scaled by log2e).  Vt: [B*H][DH][S] bf16.
// Swapped QK^T (16x16x32): lane(li,g) owns S^T[key=16n+4g+rr][q=li].
// PV (16x16x16): B-frag = k=4g+{0..3}, col=li -> P packs in-lane, shuffle-free.
// V frags pulled LDS->regs one tile early, so PV(t-1) is register-only and can't race
// the stage of tile t+1. Named even/odd register sets (rule #20: static indexing).
__global__ __launch_bounds__(256) void attn_mfma_kernel(
    const __hip_bfloat16* __restrict__ Qp,
    const __hip_bfloat16* __restrict__ Kp,
    const __hip_bfloat16* __restrict__ Vt,
    const int* __restrict__ thresholds,
    const float* __restrict__ Vsum,
    __hip_bfloat16* __restrict__ AO) {
    __shared__ char lds[32768];   // sK[2][8KB] | sVT[2][8KB]
    char* sK  = lds;
    char* sVT = lds + 16384;

    const int t = threadIdx.x, lane = t & 63, w = t >> 6;   // w in {0..3}
    const int g = lane >> 4, li = lane & 15;
    const int bh = blockIdx.x, b = bh >> 4, h = bh & 15;
    const int q0 = blockIdx.y * 64;
    const int thresh = thresholds[b];
    const int loop_end = min(SEQ, ((thresh + 63) >> 6) << 6);
    const int nt = loop_end >> 6;   // >= 1
    const __hip_bfloat16* Qb = Qp + (size_t)bh * SEQ * DH;
    const __hip_bfloat16* Kb = Kp + (size_t)bh * SEQ * DH;
    const __hip_bfloat16* Vb = Vt + (size_t)bh * DH * SEQ;

    // Q as B-fragment (col=q): lane holds Q[q0+w*16+li][kb*32+g*8 ..+8]
    short8 qf[2];
#pragma unroll
    for (int kb = 0; kb < 2; ++kb)
        qf[kb] = *(const short8*)(Qb + (size_t)(q0 + w * 16 + li) * DH + kb * 32 + g * 8);

    f32x4 Oacc[4] = {};
    float mrun = NEG_INF, lrun = 0.f;

    auto stageK = [&](int bb, int kv) {
#pragma unroll
        for (int i = 0; i < 2; ++i) {
            int o = i * 4096 + w * 1024 + lane * 16;
            int key = o >> 7, slot = (o & 127) >> 4;
            __builtin_amdgcn_global_load_lds(
                AS1C(Kb + (size_t)(kv + key) * DH + ((slot ^ (key & 7)) << 3)),
                AS3(sK + bb * 8192 + i * 4096 + w * 1024), 16, 0, 0);
        }
    };
    auto stageV = [&](int bb, int kv) {
#pragma unroll
        for (int i = 0; i < 2; ++i) {
            int o = i * 4096 + w * 1024 + lane * 16;
            int dh = o >> 7, slot = (o & 127) >> 4;
            __builtin_amdgcn_global_load_lds(
                AS1C(Vb + (size_t)dh * SEQ + kv + ((slot ^ (dh & 7)) << 3)),
                AS3(sVT + bb * 8192 + i * 4096 + w * 1024), 16, 0, 0);
        }
    };

    // named even/odd state (static indexing; no runtime-indexed register arrays)
    f32x4 S_e[4], S_o[4];
    short4v V_e[16], V_o[16];

#define QK_TILE(SS, kbase, kv0_)                                                           \
    {                                                                                      \
        _Pragma("unroll")                                                                  \
        for (int n = 0; n < 4; ++n) {                                                      \
            SS[n][0] = 0.f; SS[n][1] = 0.f; SS[n][2] = 0.f; SS[n][3] = 0.f;                \
        }                                                                                  \
        __builtin_amdgcn_s_setprio(1);                                                     \
        _Pragma("unroll")                                                                  \
        for (int kb = 0; kb < 2; ++kb) {                                                   \
            short8 kf[4];                                                                  \
            _Pragma("unroll")                                                              \
            for (int n = 0; n < 4; ++n) {                                                  \
                int key = 16 * n + li;                                                     \
                kf[n] = *(const short8*)((kbase) + key * 128 +                             \
                                         (((4 * kb + g) ^ (key & 7)) << 4));               \
            }                                                                              \
            _Pragma("unroll")                                                              \
            for (int n = 0; n < 4; ++n)                                                    \
                SS[n] = __builtin_amdgcn_mfma_f32_16x16x32_bf16(kf[n], qf[kb], SS[n], 0, 0, 0); \
        }                                                                                  \
        __builtin_amdgcn_s_setprio(0);                                                     \
        if ((kv0_) + 64 > thresh) {                                                        \
            int tr = thresh - (kv0_) - 4 * g;                                              \
            _Pragma("unroll")                                                              \
            for (int n = 0; n < 4; ++n)                                                    \
                _Pragma("unroll")                                                          \
                for (int rr = 0; rr < 4; ++rr)                                             \
                    if (16 * n + rr >= tr) SS[n][rr] = MASKB2;                             \
        }                                                                                  \
    }

#define VLOAD(VR, vbase)                                                                   \
    {                                                                                      \
        _Pragma("unroll")                                                                  \
        for (int ks = 0; ks < 4; ++ks) {                                                   \
            int slot = 2 * ks + (g >> 1);                                                  \
            _Pragma("unroll")                                                              \
            for (int n = 0; n < 4; ++n) {                                                  \
                int dh = 16 * n + li;                                                      \
                VR[4 * ks + n] = *(const short4v*)((vbase) + dh * 128 +                    \
                                  ((slot ^ (dh & 7)) << 4) + 8 * (g & 1));                 \
            }                                                                              \
        }                                                                                  \
    }

#define SMPV(SP, VP)                                                                       \
    {                                                                                      \
        float mx = SP[0][0];                                                               \
        _Pragma("unroll")                                                                  \
        for (int n = 0; n < 4; ++n)                                                        \
            _Pragma("unroll")                                                              \
            for (int rr = 0; rr < 4; ++rr) mx = fmaxf(mx, SP[n][rr]);                      \
        mx = fmaxf(mx, __shfl_xor(mx, 16));                                                \
        mx = fmaxf(mx, __shfl_xor(mx, 32));                                                \
        if (__any(mx > mrun + DEFER_THR)) {                                                \
            float mn = fmaxf(mrun, mx);                                                    \
            float alpha = fexp2(mrun - mn);                                                \
            lrun *= alpha;                                                                 \
            _Pragma("unroll")                                                              \
            for (int n = 0; n < 4; ++n)                                                    \
                _Pragma("unroll")                                                          \
                for (int rr = 0; rr < 4; ++rr) Oacc[n][rr] *= alpha;                       \
            mrun = mn;                                                                     \
        }                                                                                  \
        short4v pb[4];                                                                     \
        float rs = 0.f;                                                                    \
        _Pragma("unroll")                                                                  \
        for (int n = 0; n < 4; ++n) {                                                      \
            _Pragma("unroll")                                                              \
            for (int rr = 0; rr < 4; ++rr) {                                               \
                float p = fexp2(SP[n][rr] - mrun);                                         \
                SP[n][rr] = p;                                                             \
                rs += p;                                                                   \
            }                                                                              \
            PB u;                                                                          \
            u.u[0] = pk2(SP[n][0], SP[n][1]);                                              \
            u.u[1] = pk2(SP[n][2], SP[n][3]);                                              \
            pb[n] = u.s4;                                                                  \
        }                                                                                  \
        rs += __shfl_xor(rs, 16);                                                          \
        rs += __shfl_xor(rs, 32);                                                          \
        lrun += rs;                                                                        \
        __builtin_amdgcn_s_setprio(1);                                                     \
        _Pragma("unroll")                                                                  \
        for (int ks = 0; ks < 4; ++ks)                                                     \
            _Pragma("unroll")                                                              \
            for (int n = 0; n < 4; ++n)                                                    \
                Oacc[n] = __builtin_amdgcn_mfma_f32_16x16x16bf16_1k(VP[4 * ks + n], pb[ks],\
                                                                    Oacc[n], 0, 0, 0);     \
        __builtin_amdgcn_s_setprio(0);                                                     \
    }

    // prologue: tile 0 into buf0
    stageK(0, 0); stageV(0, 0);
    asm volatile("s_waitcnt vmcnt(0)" ::: "memory");
    __syncthreads();

    // peeled iter 0 (tile 0, even): no prev to finish
    if (nt > 1) { stageK(1, 64); stageV(1, 64); }
    QK_TILE(S_e, sK, 0);
    VLOAD(V_e, sVT);
    if (nt > 1) {
        asm volatile("s_waitcnt vmcnt(0)" ::: "memory");
        __syncthreads();
    }

    int tt = 1;
    while (tt < nt) {
        // tile tt (odd): buf1; finish tile tt-1 (even) from registers
        {
            int kv0 = tt << 6;
            if (tt + 1 < nt) { stageK(0, kv0 + 64); stageV(0, kv0 + 64); }
            QK_TILE(S_o, sK + 8192, kv0);
            VLOAD(V_o, sVT + 8192);
            SMPV(S_e, V_e);
            if (tt + 1 < nt) {
                asm volatile("s_waitcnt vmcnt(0)" ::: "memory");
                __syncthreads();
            }
        }
        ++tt;
        if (tt >= nt) break;
        // tile tt (even): buf0; finish tile tt-1 (odd)
        {
            int kv0 = tt << 6;
            if (tt + 1 < nt) { stageK(1, kv0 + 64); stageV(1, kv0 + 64); }
            QK_TILE(S_e, sK, kv0);
            VLOAD(V_e, sVT);
            SMPV(S_o, V_o);
            if (tt + 1 < nt) {
                asm volatile("s_waitcnt vmcnt(0)" ::: "memory");
                __syncthreads();
            }
        }
        ++tt;
    }

    // finish last tile (parity of nt-1)
    if (nt & 1) { SMPV(S_e, V_e); }
    else        { SMPV(S_o, V_o); }

    // ---- analytic masked tail: keys in [loop_end, SEQ) all have score MASKB2 ----
    int nmask = SEQ - loop_end;
    if (nmask > 0) {
        const float* vs = Vsum + bh * DH;
        f32x4 vsf[4];
#pragma unroll
        for (int n = 0; n < 4; ++n) vsf[n] = *(const f32x4*)(vs + 16 * n + 4 * g);
        float pu = fexp2(MASKB2 - mrun);   // mrun >= MASKB2 always
        lrun += (float)nmask * pu;
#pragma unroll
        for (int n = 0; n < 4; ++n)
#pragma unroll
            for (int rr = 0; rr < 4; ++rr) Oacc[n][rr] += pu * vsf[n][rr];
    }

    // ---- epilogue: normalize, write bf16 (8B stores) ----
    float linv = 1.0f / lrun;
    int q = q0 + w * 16 + li;
#pragma unroll
    for (int n = 0; n < 4; ++n) {
        __hip_bfloat16 o4[4];
#pragma unroll
        for (int rr = 0; rr < 4; ++rr) o4[rr] = __float2bfloat16(Oacc[n][rr] * linv);
        *(short4*)(AO + (size_t)(b * SEQ + q) * D_MODEL + h * DH + 16 * n + 4 * g) =
            *(short4*)o4;
    }
#undef QK_TILE
#undef VLOAD
#undef SMPV
}

extern "C" void kernel_launch(void* const* d_in, const int* in_sizes, int n_in,
                              void* d_out, int out_size, void* d_ws, size_t ws_size,
                              hipStream_t stream) {
    const float* queries    = (const float*)d_in[0];
    const float* keys       = (const float*)d_in[1];
    const float* values     = (const float*)d_in[2];
    const int*   thresholds = (const int*)d_in[3];
    const float* Wq = (const float*)d_in[4];
    const float* bq = (const float*)d_in[5];
    const float* Wk = (const float*)d_in[6];
    const float* bk = (const float*)d_in[7];
    const float* Wv = (const float*)d_in[8];
    const float* bv = (const float*)d_in[9];
    const float* W  = (const float*)d_in[10];
    const float* Wo = (const float*)d_in[11];
    const float* bo = (const float*)d_in[12];
    float* out = (float*)d_out;

    char* wsb = (char*)d_ws;
    float* bq2  = (float*)wsb;                         // 4 KB
    float* Vsum = (float*)(wsb + 4096);                // 8 KB
    float* Wq2  = (float*)(wsb + 16384);               // 4 MB
    __hip_bfloat16* WqT = (__hip_bfloat16*)(wsb + 16384 + (4 << 20));
    __hip_bfloat16* WkT = WqT + (1 << 20);
    __hip_bfloat16* WvT = WkT + (1 << 20);
    __hip_bfloat16* WoT = WvT + (1 << 20);
    __hip_bfloat16* QpB = WoT + (1 << 20);
    __hip_bfloat16* KpB = QpB + (1 << 22);
    __hip_bfloat16* VtB = KpB + (1 << 22);
    __hip_bfloat16* AOB = VtB + (1 << 22);

    fold_kernel<<<4100, 256, 0, stream>>>(Wq, bq, W, Wq2, bq2);
    transpose4_kernel<<<dim3(32, 32, 4), 256, 0, stream>>>(Wq2, Wk, Wv, Wo,
                                                           WqT, WkT, WvT, WoT);

    gemm_qkv_kernel<<<dim3(8, 32, 3), 256, 0, stream>>>(queries, keys, values,
                                                        WqT, WkT, WvT,
                                                        bq2, bk, bv, QpB, KpB, VtB);
    vsum_kernel<<<32, 256, 0, stream>>>(VtB, thresholds, Vsum);

    attn_mfma_kernel<<<dim3(32, 32), 256, 0, stream>>>(QpB, KpB, VtB, thresholds, Vsum, AOB);

    gemm_out_kernel<<<dim3(8, 32), 256, 0, stream>>>(AOB, WoT, bo, out);
}

// Round 14
// 226.194 us; speedup vs baseline: 1.0991x; 1.0991x over previous
//
#include <hip/hip_runtime.h>
#include <hip/hip_bf16.h>

#define D_MODEL 1024
#define NHEADS  16
#define DH      64
#define SEQ     2048
#define BATCH   2

#define LOG2E 1.4426950408889634f
#define MASKB2 (-1e-6f * LOG2E)   // mask value in exp2 domain
#define DEFER_THR 11.5456f        // 8 * log2e
#define NEG_INF (-__builtin_inff())

typedef __attribute__((ext_vector_type(8))) short short8;
typedef __attribute__((ext_vector_type(4))) short short4v;
typedef __attribute__((ext_vector_type(4))) float f32x4;

#define AS1C(p) ((const __attribute__((address_space(1))) void*)(p))
#define AS3(p)  ((__attribute__((address_space(3))) void*)(p))

union PB { short4v s4; unsigned int u[2]; };

static __device__ __forceinline__ float fexp2(float x) {
    return __builtin_amdgcn_exp2f(x);   // v_exp_f32
}

static __device__ __forceinline__ unsigned int pk2(float lo, float hi) {
    __hip_bfloat16 a = __float2bfloat16(lo), b = __float2bfloat16(hi);
    unsigned short au = *(unsigned short*)&a, bu = *(unsigned short*)&b;
    return (unsigned int)au | ((unsigned int)bu << 16);
}

// ---------------- fold bilinear W into Wq (+log2e), R4 access pattern ----------------
__global__ __launch_bounds__(256) void fold_kernel(const float* __restrict__ Wq,
                                                   const float* __restrict__ bq,
                                                   const float* __restrict__ W,
                                                   float* __restrict__ Wq2,
                                                   float* __restrict__ bq2) {
    if (blockIdx.x < 4096) {
        int idx = blockIdx.x * 256 + threadIdx.x;   // over D*D
        int row = idx >> 10;                        // block-uniform
        int col = idx & 1023;
        int h = col >> 6, j = col & 63;
        const float* wqr = Wq + (size_t)row * D_MODEL + h * DH;
        float s = 0.f;
#pragma unroll
        for (int d = 0; d < DH; ++d) s += wqr[d] * W[d * DH + j];
        Wq2[idx] = s * LOG2E;
    } else {
        int col = (blockIdx.x - 4096) * 256 + threadIdx.x;
        int h = col >> 6, j = col & 63;
        float s = 0.f;
#pragma unroll
        for (int d = 0; d < DH; ++d) s += bq[h * DH + d] * W[d * DH + j];
        bq2[col] = s * LOG2E;
    }
}

// ---------------- fp32 -> bf16, all three inputs in one launch ----------------
__global__ __launch_bounds__(256) void convert3_kernel(const float* __restrict__ q,
                                                       const float* __restrict__ k,
                                                       const float* __restrict__ v,
                                                       __hip_bfloat16* __restrict__ oq,
                                                       __hip_bfloat16* __restrict__ ok,
                                                       __hip_bfloat16* __restrict__ ov) {
    int z = blockIdx.x >> 11;                      // 2048 blocks per array
    int i = (blockIdx.x & 2047) * 256 + threadIdx.x;
    const float* in = (z == 0) ? q : (z == 1) ? k : v;
    __hip_bfloat16* out = (z == 0) ? oq : (z == 1) ? ok : ov;
    float4 a = *(const float4*)(in + (size_t)i * 8);
    float4 b = *(const float4*)(in + (size_t)i * 8 + 4);
    __hip_bfloat16 o[8];
    o[0] = __float2bfloat16(a.x); o[1] = __float2bfloat16(a.y);
    o[2] = __float2bfloat16(a.z); o[3] = __float2bfloat16(a.w);
    o[4] = __float2bfloat16(b.x); o[5] = __float2bfloat16(b.y);
    o[6] = __float2bfloat16(b.z); o[7] = __float2bfloat16(b.w);
    *(short8*)(out + (size_t)i * 8) = *(short8*)o;
}

// ---------------- transpose+convert 4 weight matrices in one launch ----------------
__global__ __launch_bounds__(256) void transpose4_kernel(const float* __restrict__ W0,
                                                         const float* __restrict__ W1,
                                                         const float* __restrict__ W2,
                                                         const float* __restrict__ W3,
                                                         __hip_bfloat16* __restrict__ T0,
                                                         __hip_bfloat16* __restrict__ T1,
                                                         __hip_bfloat16* __restrict__ T2,
                                                         __hip_bfloat16* __restrict__ T3) {
    __shared__ float sT[32][33];
    int z = blockIdx.z;
    const float* Win = (z == 0) ? W0 : (z == 1) ? W1 : (z == 2) ? W2 : W3;
    __hip_bfloat16* Wt = (z == 0) ? T0 : (z == 1) ? T1 : (z == 2) ? T2 : T3;
    int n0 = blockIdx.x * 32, k0 = blockIdx.y * 32;
    int tx = threadIdx.x & 31, ty = threadIdx.x >> 5;  // ty 0..7
#pragma unroll
    for (int i = 0; i < 4; ++i)
        sT[ty + i * 8][tx] = Win[(size_t)(k0 + ty + i * 8) * D_MODEL + n0 + tx];
    __syncthreads();
#pragma unroll
    for (int i = 0; i < 4; ++i)
        Wt[(size_t)(n0 + ty + i * 8) * D_MODEL + k0 + tx] = __float2bfloat16(sT[tx][ty + i * 8]);
}

// ================= GEMM core (128x128 tile, BK=32, 2-phase dbuf) — R12-proven =============
#define GEMM_CORE(A_, BT_)                                                                  \
    __shared__ __hip_bfloat16 sA[2][128 * 32];                                              \
    __shared__ __hip_bfloat16 sB[2][128 * 32];                                              \
    const int t = threadIdx.x;                                                              \
    const int lane = t & 63, w = t >> 6;                                                    \
    const int g = lane >> 4, li = lane & 15;                                                \
    const int r0 = blockIdx.y * 128, c0 = blockIdx.x * 128;                                 \
    const int wr = (w >> 1) * 64, wc = (w & 1) * 64;                                        \
    f32x4 acc[4][4] = {};                                                                   \
    auto stage = [&](int bb, int k0) {                                                      \
        _Pragma("unroll")                                                                   \
        for (int i = 0; i < 2; ++i) {                                                       \
            int o = (i * 4 + w) * 1024 + lane * 16;                                         \
            int row = o >> 6, ce = (o & 63) >> 1;                                           \
            __builtin_amdgcn_global_load_lds(AS1C(A_ + (size_t)(r0 + row) * 1024 + k0 + ce),\
                                             AS3((char*)sA[bb] + (i * 4 + w) * 1024), 16, 0, 0); \
            __builtin_amdgcn_global_load_lds(AS1C(BT_ + (size_t)(c0 + row) * 1024 + k0 + ce),\
                                             AS3((char*)sB[bb] + (i * 4 + w) * 1024), 16, 0, 0); \
        }                                                                                   \
    };                                                                                      \
    stage(0, 0);                                                                            \
    asm volatile("s_waitcnt vmcnt(0)" ::: "memory");                                        \
    __syncthreads();                                                                        \
    int cur = 0;                                                                            \
    for (int k0 = 0; k0 < 1024; k0 += 32) {                                                 \
        if (k0 + 32 < 1024) stage(cur ^ 1, k0 + 32);                                        \
        short8 af[4], bf[4];                                                                \
        _Pragma("unroll")                                                                   \
        for (int m = 0; m < 4; ++m)                                                         \
            af[m] = *(const short8*)(sA[cur] + (wr + m * 16 + li) * 32 + g * 8);            \
        _Pragma("unroll")                                                                   \
        for (int n = 0; n < 4; ++n)                                                         \
            bf[n] = *(const short8*)(sB[cur] + (wc + n * 16 + li) * 32 + g * 8);            \
        _Pragma("unroll")                                                                   \
        for (int m = 0; m < 4; ++m)                                                         \
            _Pragma("unroll")                                                               \
            for (int n = 0; n < 4; ++n)                                                     \
                acc[m][n] = __builtin_amdgcn_mfma_f32_16x16x32_bf16(af[m], bf[n], acc[m][n], 0, 0, 0); \
        asm volatile("s_waitcnt vmcnt(0)" ::: "memory");                                    \
        __syncthreads();                                                                    \
        cur ^= 1;                                                                           \
    }

// ---------------- QKV projections, one launch (grid.z selects which) ----------------
// z=0: Q -> Qp [B*H][S][DH];  z=1: K -> Kp same;  z=2: V -> Vt [B*H][DH][S]
__global__ __launch_bounds__(256) void gemm_qkv_kernel(
    const __hip_bfloat16* __restrict__ Xq, const __hip_bfloat16* __restrict__ Xk,
    const __hip_bfloat16* __restrict__ Xv,
    const __hip_bfloat16* __restrict__ WqT, const __hip_bfloat16* __restrict__ WkT,
    const __hip_bfloat16* __restrict__ WvT,
    const float* __restrict__ bq2, const float* __restrict__ bk, const float* __restrict__ bv,
    __hip_bfloat16* __restrict__ Qp, __hip_bfloat16* __restrict__ Kp,
    __hip_bfloat16* __restrict__ Vt) {
    const int z = blockIdx.z;
    const __hip_bfloat16* A  = (z == 0) ? Xq  : (z == 1) ? Xk  : Xv;
    const __hip_bfloat16* BT = (z == 0) ? WqT : (z == 1) ? WkT : WvT;
    const float* bias        = (z == 0) ? bq2 : (z == 1) ? bk  : bv;
    __hip_bfloat16* C        = (z == 0) ? Qp  : (z == 1) ? Kp  : Vt;

    GEMM_CORE(A, BT)

#pragma unroll
    for (int m = 0; m < 4; ++m) {
#pragma unroll
        for (int n = 0; n < 4; ++n) {
            int col = c0 + wc + n * 16 + li;
            float bs = bias[col];
            int row0 = r0 + wr + m * 16 + g * 4;
            int h = col >> 6, d = col & 63;
            if (z == 2) {
                int b = row0 >> 11, s0 = row0 & 2047;
                __hip_bfloat16 o4[4];
#pragma unroll
                for (int r = 0; r < 4; ++r) o4[r] = __float2bfloat16(acc[m][n][r] + bs);
                *(short4*)(C + (((size_t)(b * NHEADS + h)) * DH + d) * SEQ + s0) = *(short4*)o4;
            } else {
#pragma unroll
                for (int r = 0; r < 4; ++r) {
                    int row = row0 + r;
                    int b = row >> 11, s = row & 2047;
                    C[(((size_t)(b * NHEADS + h)) * SEQ + s) * DH + d] =
                        __float2bfloat16(acc[m][n][r] + bs);
                }
            }
        }
    }
}

// ---------------- output projection (fp32 out) ----------------
__global__ __launch_bounds__(256) void gemm_out_kernel(
    const __hip_bfloat16* __restrict__ A, const __hip_bfloat16* __restrict__ BT,
    const float* __restrict__ bias, float* __restrict__ C) {
    GEMM_CORE(A, BT)
#pragma unroll
    for (int m = 0; m < 4; ++m) {
#pragma unroll
        for (int n = 0; n < 4; ++n) {
            int col = c0 + wc + n * 16 + li;
            float bs = bias[col];
            int row0 = r0 + wr + m * 16 + g * 4;
#pragma unroll
            for (int r = 0; r < 4; ++r)
                C[(size_t)(row0 + r) * D_MODEL + col] = acc[m][n][r] + bs;
        }
    }
}

// ---------------- Vsum[bh][dh] = sum_{s >= loop_end_b} Vt[bh][dh][s]  (f32) ----------------
__global__ __launch_bounds__(256) void vsum_kernel(const __hip_bfloat16* __restrict__ Vt,
                                                   const int* __restrict__ thresholds,
                                                   float* __restrict__ Vsum) {
    int bh = blockIdx.x, b = bh >> 4;
    int thresh = thresholds[b];
    int loop_end = min(SEQ, ((thresh + 63) >> 6) << 6);
    int t = threadIdx.x;
    int dh = t >> 2, sub = t & 3;
    const __hip_bfloat16* row = Vt + ((size_t)bh * DH + dh) * SEQ;
    float s = 0.f;
    for (int s0 = loop_end + sub * 8; s0 < SEQ; s0 += 32) {
        short8 v = *(const short8*)(row + s0);
#pragma unroll
        for (int j = 0; j < 8; ++j) {
            unsigned short us = (unsigned short)v[j];
            s += __bfloat162float(*(__hip_bfloat16*)&us);
        }
    }
    s += __shfl_xor(s, 1);
    s += __shfl_xor(s, 2);
    if (sub == 0) Vsum[bh * DH + dh] = s;
}

// ------ flash MFMA attention: SINGLE-WAVE blocks, no barriers, private K-LDS + V-regs ------
// 64 threads/block, 32 q-rows/wave, 2048 blocks. K double-buffered in private 16KB LDS via
// global_load_lds (prefetch 1 tile ahead); V prefetched into REGISTERS 1 tile ahead (T14,
// named Va/Vb sets, statically indexed — rule 20). Counted vmcnt works here because there
// is NO barrier for the compiler to drain (single-wave block). Waves fully independent.
// Qp/Kp: [B*H][S][DH] bf16 (Q pre-scaled by log2e).  Vt: [B*H][DH][S] bf16.
// Swapped QK^T (16x16x32): lane(li,g) owns S^T[key=16n+4g+rr][q=li] per mq.
// PV (16x16x16): A-frag = V^T regs, B-frag = P packed in-lane (shuffle-free).
__global__ __launch_bounds__(64) void attn_mfma_kernel(
    const __hip_bfloat16* __restrict__ Qp,
    const __hip_bfloat16* __restrict__ Kp,
    const __hip_bfloat16* __restrict__ Vt,
    const int* __restrict__ thresholds,
    const float* __restrict__ Vsum,
    __hip_bfloat16* __restrict__ AO) {
    __shared__ char sK[16384];   // [2][8KB] K double-buffer, private to this wave

    const int lane = threadIdx.x;               // 0..63
    const int g = lane >> 4, li = lane & 15;
    const int bh = blockIdx.x, b = bh >> 4, h = bh & 15;
    const int q0 = blockIdx.y * 32;
    const int thresh = thresholds[b];
    const int loop_end = min(SEQ, ((thresh + 63) >> 6) << 6);
    const int nt = loop_end >> 6;   // >= 1
    const __hip_bfloat16* Qb = Qp + (size_t)bh * SEQ * DH;
    const __hip_bfloat16* Kb = Kp + (size_t)bh * SEQ * DH;
    const __hip_bfloat16* Vb = Vt + (size_t)bh * DH * SEQ;

    // Q as B-fragment (col=q): lane holds Q[q0+mq*16+li][kb*32+g*8 ..+8]
    short8 qf[2][2];
#pragma unroll
    for (int mq = 0; mq < 2; ++mq)
#pragma unroll
        for (int kb = 0; kb < 2; ++kb)
            qf[mq][kb] = *(const short8*)(Qb + (size_t)(q0 + mq * 16 + li) * DH +
                                          kb * 32 + g * 8);

    f32x4 Oacc[2][4] = {};
    float mrun[2] = {NEG_INF, NEG_INF};
    float lrun[2] = {0.f, 0.f};

    auto stageK = [&](int bb, int kv) {
#pragma unroll
        for (int i = 0; i < 8; ++i) {
            int o = i * 1024 + lane * 16;
            int key = o >> 7, slot = (o & 127) >> 4;
            __builtin_amdgcn_global_load_lds(
                AS1C(Kb + (size_t)(kv + key) * DH + ((slot ^ (key & 7)) << 3)),
                AS3(sK + bb * 8192 + i * 1024), 16, 0, 0);
        }
    };

    short4v Va[16], Vb_r[16];

#define VLOAD(VR, kv0_)                                                                    \
    {                                                                                      \
        _Pragma("unroll")                                                                  \
        for (int ks = 0; ks < 4; ++ks)                                                     \
            _Pragma("unroll")                                                              \
            for (int n = 0; n < 4; ++n)                                                    \
                VR[4 * ks + n] = *(const short4v*)(Vb + (size_t)(16 * n + li) * SEQ +      \
                                                   (kv0_) + 16 * ks + 4 * g);              \
    }

#define ITER(VC, VN)                                                                       \
    {                                                                                      \
        int kv0 = tt << 6;                                                                 \
        bool more = (tt + 1 < nt);                                                         \
        if (more) {                                                                        \
            stageK(cur ^ 1, kv0 + 64);                                                     \
            VLOAD(VN, kv0 + 64);                                                           \
            asm volatile("s_waitcnt vmcnt(24)" ::: "memory");                              \
        } else {                                                                           \
            asm volatile("s_waitcnt vmcnt(16)" ::: "memory");                              \
        }                                                                                  \
        f32x4 S[2][4] = {};                                                                \
        __builtin_amdgcn_s_setprio(1);                                                     \
        _Pragma("unroll")                                                                  \
        for (int kb = 0; kb < 2; ++kb) {                                                   \
            short8 kf[4];                                                                  \
            _Pragma("unroll")                                                              \
            for (int n = 0; n < 4; ++n) {                                                  \
                int key = 16 * n + li;                                                     \
                kf[n] = *(const short8*)(sK + cur * 8192 + key * 128 +                     \
                                         (((4 * kb + g) ^ (key & 7)) << 4));               \
            }                                                                              \
            _Pragma("unroll")                                                              \
            for (int mq = 0; mq < 2; ++mq)                                                 \
                _Pragma("unroll")                                                          \
                for (int n = 0; n < 4; ++n)                                                \
                    S[mq][n] = __builtin_amdgcn_mfma_f32_16x16x32_bf16(kf[n], qf[mq][kb],  \
                                                                      S[mq][n], 0, 0, 0);  \
        }                                                                                  \
        __builtin_amdgcn_s_setprio(0);                                                     \
        if (kv0 + 64 > thresh) {                                                           \
            int tr = thresh - kv0 - 4 * g;                                                 \
            _Pragma("unroll")                                                              \
            for (int n = 0; n < 4; ++n)                                                    \
                _Pragma("unroll")                                                          \
                for (int rr = 0; rr < 4; ++rr)                                             \
                    if (16 * n + rr >= tr) { S[0][n][rr] = MASKB2; S[1][n][rr] = MASKB2; } \
        }                                                                                  \
        float pmax[2];                                                                     \
        _Pragma("unroll")                                                                  \
        for (int mq = 0; mq < 2; ++mq) {                                                   \
            float mx = S[mq][0][0];                                                        \
            _Pragma("unroll")                                                              \
            for (int n = 0; n < 4; ++n)                                                    \
                _Pragma("unroll")                                                          \
                for (int rr = 0; rr < 4; ++rr) mx = fmaxf(mx, S[mq][n][rr]);               \
            mx = fmaxf(mx, __shfl_xor(mx, 16));                                            \
            mx = fmaxf(mx, __shfl_xor(mx, 32));                                            \
            pmax[mq] = mx;                                                                 \
        }                                                                                  \
        bool need = (pmax[0] > mrun[0] + DEFER_THR) || (pmax[1] > mrun[1] + DEFER_THR);    \
        if (__any(need)) {                                                                 \
            _Pragma("unroll")                                                              \
            for (int mq = 0; mq < 2; ++mq) {                                               \
                float mn = fmaxf(mrun[mq], pmax[mq]);                                      \
                float alpha = fexp2(mrun[mq] - mn);                                        \
                lrun[mq] *= alpha;                                                         \
                _Pragma("unroll")                                                          \
                for (int n = 0; n < 4; ++n)                                                \
                    _Pragma("unroll")                                                      \
                    for (int rr = 0; rr < 4; ++rr) Oacc[mq][n][rr] *= alpha;               \
                mrun[mq] = mn;                                                             \
            }                                                                              \
        }                                                                                  \
        short4v pb[2][4];                                                                  \
        _Pragma("unroll")                                                                  \
        for (int mq = 0; mq < 2; ++mq) {                                                   \
            float rs = 0.f;                                                                \
            _Pragma("unroll")                                                              \
            for (int n = 0; n < 4; ++n) {                                                  \
                _Pragma("unroll")                                                          \
                for (int rr = 0; rr < 4; ++rr) {                                           \
                    float p = fexp2(S[mq][n][rr] - mrun[mq]);                              \
                    S[mq][n][rr] = p;                                                      \
                    rs += p;                                                               \
                }                                                                          \
                PB u;                                                                      \
                u.u[0] = pk2(S[mq][n][0], S[mq][n][1]);                                    \
                u.u[1] = pk2(S[mq][n][2], S[mq][n][3]);                                    \
                pb[mq][n] = u.s4;                                                          \
            }                                                                              \
            rs += __shfl_xor(rs, 16);                                                      \
            rs += __shfl_xor(rs, 32);                                                      \
            lrun[mq] += rs;                                                                \
        }                                                                                  \
        __builtin_amdgcn_s_setprio(1);                                                     \
        _Pragma("unroll")                                                                  \
        for (int ks = 0; ks < 4; ++ks)                                                     \
            _Pragma("unroll")                                                              \
            for (int n = 0; n < 4; ++n)                                                    \
                _Pragma("unroll")                                                          \
                for (int mq = 0; mq < 2; ++mq)                                             \
                    Oacc[mq][n] = __builtin_amdgcn_mfma_f32_16x16x16bf16_1k(               \
                        VC[4 * ks + n], pb[mq][ks], Oacc[mq][n], 0, 0, 0);                 \
        __builtin_amdgcn_s_setprio(0);                                                     \
    }

    // prologue: tile 0 -> buf0 + Va
    stageK(0, 0);
    VLOAD(Va, 0);

    int cur = 0, tt = 0;
    while (true) {
        ITER(Va, Vb_r);
        ++tt; cur ^= 1;
        if (tt >= nt) break;
        ITER(Vb_r, Va);
        ++tt; cur ^= 1;
        if (tt >= nt) break;
    }
#undef ITER
#undef VLOAD

    // ---- analytic masked tail: keys in [loop_end, SEQ) all have score MASKB2 ----
    int nmask = SEQ - loop_end;
    if (nmask > 0) {
        const float* vs = Vsum + bh * DH;
        f32x4 vsf[4];
#pragma unroll
        for (int n = 0; n < 4; ++n) vsf[n] = *(const f32x4*)(vs + 16 * n + 4 * g);
#pragma unroll
        for (int mq = 0; mq < 2; ++mq) {
            float pu = fexp2(MASKB2 - mrun[mq]);   // mrun >= MASKB2 always
            lrun[mq] += (float)nmask * pu;
#pragma unroll
            for (int n = 0; n < 4; ++n)
#pragma unroll
                for (int rr = 0; rr < 4; ++rr) Oacc[mq][n][rr] += pu * vsf[n][rr];
        }
    }

    // ---- epilogue: normalize, write bf16 (8B stores) ----
#pragma unroll
    for (int mq = 0; mq < 2; ++mq) {
        float linv = 1.0f / lrun[mq];
        int q = q0 + mq * 16 + li;
#pragma unroll
        for (int n = 0; n < 4; ++n) {
            __hip_bfloat16 o4[4];
#pragma unroll
            for (int rr = 0; rr < 4; ++rr) o4[rr] = __float2bfloat16(Oacc[mq][n][rr] * linv);
            *(short4*)(AO + (size_t)(b * SEQ + q) * D_MODEL + h * DH + 16 * n + 4 * g) =
                *(short4*)o4;
        }
    }
}

extern "C" void kernel_launch(void* const* d_in, const int* in_sizes, int n_in,
                              void* d_out, int out_size, void* d_ws, size_t ws_size,
                              hipStream_t stream) {
    const float* queries    = (const float*)d_in[0];
    const float* keys       = (const float*)d_in[1];
    const float* values     = (const float*)d_in[2];
    const int*   thresholds = (const int*)d_in[3];
    const float* Wq = (const float*)d_in[4];
    const float* bq = (const float*)d_in[5];
    const float* Wk = (const float*)d_in[6];
    const float* bk = (const float*)d_in[7];
    const float* Wv = (const float*)d_in[8];
    const float* bv = (const float*)d_in[9];
    const float* W  = (const float*)d_in[10];
    const float* Wo = (const float*)d_in[11];
    const float* bo = (const float*)d_in[12];
    float* out = (float*)d_out;

    char* wsb = (char*)d_ws;
    float* bq2  = (float*)wsb;                         // 4 KB
    float* Vsum = (float*)(wsb + 4096);                // 8 KB
    float* Wq2  = (float*)(wsb + 16384);               // 4 MB
    __hip_bfloat16* XqB = (__hip_bfloat16*)(wsb + 16384 + (4 << 20));
    __hip_bfloat16* XkB = XqB + (1 << 22);
    __hip_bfloat16* XvB = XkB + (1 << 22);
    __hip_bfloat16* WqT = XvB + (1 << 22);
    __hip_bfloat16* WkT = WqT + (1 << 20);
    __hip_bfloat16* WvT = WkT + (1 << 20);
    __hip_bfloat16* WoT = WvT + (1 << 20);
    __hip_bfloat16* QpB = WoT + (1 << 20);
    __hip_bfloat16* KpB = QpB + (1 << 22);
    __hip_bfloat16* VtB = KpB + (1 << 22);
    __hip_bfloat16* AOB = XqB;   // alias: XqB dead after Q projection

    fold_kernel<<<4100, 256, 0, stream>>>(Wq, bq, W, Wq2, bq2);
    convert3_kernel<<<6144, 256, 0, stream>>>(queries, keys, values, XqB, XkB, XvB);
    transpose4_kernel<<<dim3(32, 32, 4), 256, 0, stream>>>(Wq2, Wk, Wv, Wo,
                                                           WqT, WkT, WvT, WoT);

    gemm_qkv_kernel<<<dim3(8, 32, 3), 256, 0, stream>>>(XqB, XkB, XvB, WqT, WkT, WvT,
                                                        bq2, bk, bv, QpB, KpB, VtB);
    vsum_kernel<<<32, 256, 0, stream>>>(VtB, thresholds, Vsum);

    attn_mfma_kernel<<<dim3(32, 64), 64, 0, stream>>>(QpB, KpB, VtB, thresholds, Vsum, AOB);

    gemm_out_kernel<<<dim3(8, 32), 256, 0, stream>>>(AOB, WoT, bo, out);
}

// Round 15
// 161.272 us; speedup vs baseline: 1.5415x; 1.4026x over previous
//
#include <hip/hip_runtime.h>
#include <hip/hip_bf16.h>

#define D_MODEL 1024
#define NHEADS  16
#define DH      64
#define SEQ     2048
#define BATCH   2

#define LOG2E 1.4426950408889634f
#define MASKB2 (-1e-6f * LOG2E)   // mask value in exp2 domain
#define DEFER_THR 11.5456f        // 8 * log2e
#define NEG_INF (-__builtin_inff())

typedef __attribute__((ext_vector_type(8))) short short8;
typedef __attribute__((ext_vector_type(4))) short short4v;
typedef __attribute__((ext_vector_type(4))) float f32x4;

#define AS1C(p) ((const __attribute__((address_space(1))) void*)(p))
#define AS3(p)  ((__attribute__((address_space(3))) void*)(p))

union PB { short4v s4; unsigned int u[2]; };

static __device__ __forceinline__ float fexp2(float x) {
    return __builtin_amdgcn_exp2f(x);   // v_exp_f32
}

static __device__ __forceinline__ unsigned int pk2(float lo, float hi) {
    __hip_bfloat16 a = __float2bfloat16(lo), b = __float2bfloat16(hi);
    unsigned short au = *(unsigned short*)&a, bu = *(unsigned short*)&b;
    return (unsigned int)au | ((unsigned int)bu << 16);
}

// ------- fused fold+transpose: WqT[col][row] = log2e * (Wq @ Wbd)[row][col], bf16 -------
// Tile [32 rows x 32 cols]; coalesced reads of Wq and W, coalesced 8B writes of WqT.
// blockIdx.y == 32 computes bq2 instead.
__global__ __launch_bounds__(256) void fold_q_kernel(const float* __restrict__ Wq,
                                                     const float* __restrict__ bq,
                                                     const float* __restrict__ W,
                                                     __hip_bfloat16* __restrict__ WqT,
                                                     float* __restrict__ bq2) {
    const int t = threadIdx.x;
    const int c0 = blockIdx.x * 32;
    const int h = c0 >> 6, j0 = c0 & 63;

    if (blockIdx.y == 32) {
        if (t < 32) {
            int col = c0 + t, j = col & 63;
            float s = 0.f;
#pragma unroll
            for (int d = 0; d < DH; ++d) s += bq[h * DH + d] * W[d * DH + j];
            bq2[col] = s * LOG2E;
        }
        return;
    }

    const int r0 = blockIdx.y * 32;
    __shared__ float sWq[32][68];   // [row][d], 272B stride (16B-aligned)
    __shared__ float sW[64][36];    // [d][jloc], 144B stride (16B-aligned)
    __shared__ float sOut[32][33];  // [col][row]

    {
        int lr = t >> 3, lc8 = (t & 7) * 8;
        const float* src = Wq + (size_t)(r0 + lr) * D_MODEL + h * DH + lc8;
        *(float4*)&sWq[lr][lc8]     = *(const float4*)(src);
        *(float4*)&sWq[lr][lc8 + 4] = *(const float4*)(src + 4);
        int d = t >> 2, c8 = (t & 3) * 8;
        const float* wsrc = W + (size_t)d * DH + j0 + c8;
        *(float4*)&sW[d][c8]     = *(const float4*)(wsrc);
        *(float4*)&sW[d][c8 + 4] = *(const float4*)(wsrc + 4);
    }
    __syncthreads();

    {
        int col_loc = t & 31, rq = t >> 5;   // rq 0..7 -> rows rq*4..+3
        float acc0 = 0.f, acc1 = 0.f, acc2 = 0.f, acc3 = 0.f;
#pragma unroll
        for (int d = 0; d < 64; ++d) {
            float wv = sW[d][col_loc];
            acc0 += sWq[rq * 4 + 0][d] * wv;
            acc1 += sWq[rq * 4 + 1][d] * wv;
            acc2 += sWq[rq * 4 + 2][d] * wv;
            acc3 += sWq[rq * 4 + 3][d] * wv;
        }
        sOut[col_loc][rq * 4 + 0] = acc0 * LOG2E;
        sOut[col_loc][rq * 4 + 1] = acc1 * LOG2E;
        sOut[col_loc][rq * 4 + 2] = acc2 * LOG2E;
        sOut[col_loc][rq * 4 + 3] = acc3 * LOG2E;
    }
    __syncthreads();

    {
        int orow = t >> 3, oc4 = (t & 7) * 4;   // output col c0+orow, rows r0+oc4..+4
        __hip_bfloat16 o4[4];
#pragma unroll
        for (int i = 0; i < 4; ++i) o4[i] = __float2bfloat16(sOut[orow][oc4 + i]);
        *(short4*)(WqT + (size_t)(c0 + orow) * D_MODEL + r0 + oc4) = *(short4*)o4;
    }
}

// ------- merged prep: blocks [0,3072) transpose Wk/Wv/Wo -> bf16; [3072,9216) convert QKV ----
__global__ __launch_bounds__(256) void prep_kernel(const float* __restrict__ Wk,
                                                   const float* __restrict__ Wv,
                                                   const float* __restrict__ Wo,
                                                   __hip_bfloat16* __restrict__ WkT,
                                                   __hip_bfloat16* __restrict__ WvT,
                                                   __hip_bfloat16* __restrict__ WoT,
                                                   const float* __restrict__ q,
                                                   const float* __restrict__ k,
                                                   const float* __restrict__ v,
                                                   __hip_bfloat16* __restrict__ oq,
                                                   __hip_bfloat16* __restrict__ ok,
                                                   __hip_bfloat16* __restrict__ ov) {
    __shared__ float sT[32][33];
    int blk = blockIdx.x;
    if (blk < 3072) {
        int z = blk >> 10, r = blk & 1023;
        const float* Win = (z == 0) ? Wk : (z == 1) ? Wv : Wo;
        __hip_bfloat16* Wt = (z == 0) ? WkT : (z == 1) ? WvT : WoT;
        int n0 = (r & 31) * 32, k0 = (r >> 5) * 32;
        int tx = threadIdx.x & 31, ty = threadIdx.x >> 5;
#pragma unroll
        for (int i = 0; i < 4; ++i)
            sT[ty + i * 8][tx] = Win[(size_t)(k0 + ty + i * 8) * D_MODEL + n0 + tx];
        __syncthreads();
#pragma unroll
        for (int i = 0; i < 4; ++i)
            Wt[(size_t)(n0 + ty + i * 8) * D_MODEL + k0 + tx] =
                __float2bfloat16(sT[tx][ty + i * 8]);
    } else {
        int idx = blk - 3072;                    // 0..6143
        int z = idx >> 11;
        int i = (idx & 2047) * 256 + threadIdx.x;
        const float* in = (z == 0) ? q : (z == 1) ? k : v;
        __hip_bfloat16* out = (z == 0) ? oq : (z == 1) ? ok : ov;
        float4 a = *(const float4*)(in + (size_t)i * 8);
        float4 b = *(const float4*)(in + (size_t)i * 8 + 4);
        __hip_bfloat16 o[8];
        o[0] = __float2bfloat16(a.x); o[1] = __float2bfloat16(a.y);
        o[2] = __float2bfloat16(a.z); o[3] = __float2bfloat16(a.w);
        o[4] = __float2bfloat16(b.x); o[5] = __float2bfloat16(b.y);
        o[6] = __float2bfloat16(b.z); o[7] = __float2bfloat16(b.w);
        *(short8*)(out + (size_t)i * 8) = *(short8*)o;
    }
}

// ================= GEMM core (128x128 tile, BK=32, 2-phase dbuf) — R12-proven =============
#define GEMM_CORE(A_, BT_)                                                                  \
    __shared__ __hip_bfloat16 sA[2][128 * 32];                                              \
    __shared__ __hip_bfloat16 sB[2][128 * 32];                                              \
    const int t = threadIdx.x;                                                              \
    const int lane = t & 63, w = t >> 6;                                                    \
    const int g = lane >> 4, li = lane & 15;                                                \
    const int r0 = blockIdx.y * 128, c0 = blockIdx.x * 128;                                 \
    const int wr = (w >> 1) * 64, wc = (w & 1) * 64;                                        \
    f32x4 acc[4][4] = {};                                                                   \
    auto stage = [&](int bb, int k0) {                                                      \
        _Pragma("unroll")                                                                   \
        for (int i = 0; i < 2; ++i) {                                                       \
            int o = (i * 4 + w) * 1024 + lane * 16;                                         \
            int row = o >> 6, ce = (o & 63) >> 1;                                           \
            __builtin_amdgcn_global_load_lds(AS1C(A_ + (size_t)(r0 + row) * 1024 + k0 + ce),\
                                             AS3((char*)sA[bb] + (i * 4 + w) * 1024), 16, 0, 0); \
            __builtin_amdgcn_global_load_lds(AS1C(BT_ + (size_t)(c0 + row) * 1024 + k0 + ce),\
                                             AS3((char*)sB[bb] + (i * 4 + w) * 1024), 16, 0, 0); \
        }                                                                                   \
    };                                                                                      \
    stage(0, 0);                                                                            \
    asm volatile("s_waitcnt vmcnt(0)" ::: "memory");                                        \
    __syncthreads();                                                                        \
    int cur = 0;                                                                            \
    for (int k0 = 0; k0 < 1024; k0 += 32) {                                                 \
        if (k0 + 32 < 1024) stage(cur ^ 1, k0 + 32);                                        \
        short8 af[4], bf[4];                                                                \
        _Pragma("unroll")                                                                   \
        for (int m = 0; m < 4; ++m)                                                         \
            af[m] = *(const short8*)(sA[cur] + (wr + m * 16 + li) * 32 + g * 8);            \
        _Pragma("unroll")                                                                   \
        for (int n = 0; n < 4; ++n)                                                         \
            bf[n] = *(const short8*)(sB[cur] + (wc + n * 16 + li) * 32 + g * 8);            \
        _Pragma("unroll")                                                                   \
        for (int m = 0; m < 4; ++m)                                                         \
            _Pragma("unroll")                                                               \
            for (int n = 0; n < 4; ++n)                                                     \
                acc[m][n] = __builtin_amdgcn_mfma_f32_16x16x32_bf16(af[m], bf[n], acc[m][n], 0, 0, 0); \
        asm volatile("s_waitcnt vmcnt(0)" ::: "memory");                                    \
        __syncthreads();                                                                    \
        cur ^= 1;                                                                           \
    }

// ---------------- QKV projections, one launch (grid.z selects which) ----------------
__global__ __launch_bounds__(256) void gemm_qkv_kernel(
    const __hip_bfloat16* __restrict__ Xq, const __hip_bfloat16* __restrict__ Xk,
    const __hip_bfloat16* __restrict__ Xv,
    const __hip_bfloat16* __restrict__ WqT, const __hip_bfloat16* __restrict__ WkT,
    const __hip_bfloat16* __restrict__ WvT,
    const float* __restrict__ bq2, const float* __restrict__ bk, const float* __restrict__ bv,
    __hip_bfloat16* __restrict__ Qp, __hip_bfloat16* __restrict__ Kp,
    __hip_bfloat16* __restrict__ Vt) {
    const int z = blockIdx.z;
    const __hip_bfloat16* A  = (z == 0) ? Xq  : (z == 1) ? Xk  : Xv;
    const __hip_bfloat16* BT = (z == 0) ? WqT : (z == 1) ? WkT : WvT;
    const float* bias        = (z == 0) ? bq2 : (z == 1) ? bk  : bv;
    __hip_bfloat16* C        = (z == 0) ? Qp  : (z == 1) ? Kp  : Vt;

    GEMM_CORE(A, BT)

#pragma unroll
    for (int m = 0; m < 4; ++m) {
#pragma unroll
        for (int n = 0; n < 4; ++n) {
            int col = c0 + wc + n * 16 + li;
            float bs = bias[col];
            int row0 = r0 + wr + m * 16 + g * 4;
            int h = col >> 6, d = col & 63;
            if (z == 2) {
                int b = row0 >> 11, s0 = row0 & 2047;
                __hip_bfloat16 o4[4];
#pragma unroll
                for (int r = 0; r < 4; ++r) o4[r] = __float2bfloat16(acc[m][n][r] + bs);
                *(short4*)(C + (((size_t)(b * NHEADS + h)) * DH + d) * SEQ + s0) = *(short4*)o4;
            } else {
#pragma unroll
                for (int r = 0; r < 4; ++r) {
                    int row = row0 + r;
                    int b = row >> 11, s = row & 2047;
                    C[(((size_t)(b * NHEADS + h)) * SEQ + s) * DH + d] =
                        __float2bfloat16(acc[m][n][r] + bs);
                }
            }
        }
    }
}

// ---------------- output projection (fp32 out) ----------------
__global__ __launch_bounds__(256) void gemm_out_kernel(
    const __hip_bfloat16* __restrict__ A, const __hip_bfloat16* __restrict__ BT,
    const float* __restrict__ bias, float* __restrict__ C) {
    GEMM_CORE(A, BT)
#pragma unroll
    for (int m = 0; m < 4; ++m) {
#pragma unroll
        for (int n = 0; n < 4; ++n) {
            int col = c0 + wc + n * 16 + li;
            float bs = bias[col];
            int row0 = r0 + wr + m * 16 + g * 4;
#pragma unroll
            for (int r = 0; r < 4; ++r)
                C[(size_t)(row0 + r) * D_MODEL + col] = acc[m][n][r] + bs;
        }
    }
}

// ---------------- Vsum[bh][dh] = sum_{s >= loop_end_b} Vt[bh][dh][s]  (f32) ----------------
__global__ __launch_bounds__(256) void vsum_kernel(const __hip_bfloat16* __restrict__ Vt,
                                                   const int* __restrict__ thresholds,
                                                   float* __restrict__ Vsum) {
    int bh = blockIdx.x, b = bh >> 4;
    int thresh = thresholds[b];
    int loop_end = min(SEQ, ((thresh + 63) >> 6) << 6);
    int t = threadIdx.x;
    int dh = t >> 2, sub = t & 3;
    const __hip_bfloat16* row = Vt + ((size_t)bh * DH + dh) * SEQ;
    float s = 0.f;
    for (int s0 = loop_end + sub * 8; s0 < SEQ; s0 += 32) {
        short8 v = *(const short8*)(row + s0);
#pragma unroll
        for (int j = 0; j < 8; ++j) {
            unsigned short us = (unsigned short)v[j];
            s += __bfloat162float(*(__hip_bfloat16*)&us);
        }
    }
    s += __shfl_xor(s, 1);
    s += __shfl_xor(s, 2);
    if (sub == 0) Vsum[bh * DH + dh] = s;
}

// ---------------- flash MFMA attention (R12 structure + L2-friendly dispatch) ----------
// grid: x = q-block (fastest) so 32 consecutive blocks share one head's KV (L2-resident);
// y -> bh batch-interleaved: bh = ((y&1)<<4) | (y>>1).
__global__ __launch_bounds__(256) void attn_mfma_kernel(
    const __hip_bfloat16* __restrict__ Qp,
    const __hip_bfloat16* __restrict__ Kp,
    const __hip_bfloat16* __restrict__ Vt,
    const int* __restrict__ thresholds,
    const float* __restrict__ Vsum,
    __hip_bfloat16* __restrict__ AO) {
    __shared__ char lds[32768];   // sK[2][8KB] | sVT[2][8KB]
    char* sK  = lds;
    char* sVT = lds + 16384;

    const int t = threadIdx.x, lane = t & 63, w = t >> 6;   // w in {0..3}
    const int g = lane >> 4, li = lane & 15;
    const int bh_i = blockIdx.y;
    const int bh = ((bh_i & 1) << 4) | (bh_i >> 1);
    const int b = bh >> 4, h = bh & 15;
    const int q0 = blockIdx.x * 64;
    const int thresh = thresholds[b];
    const int loop_end = min(SEQ, ((thresh + 63) >> 6) << 6);
    const __hip_bfloat16* Qb = Qp + (size_t)bh * SEQ * DH;
    const __hip_bfloat16* Kb = Kp + (size_t)bh * SEQ * DH;
    const __hip_bfloat16* Vb = Vt + (size_t)bh * DH * SEQ;

    // Q as B-fragment (col=q): lane holds Q[q0+w*16+li][kb*32+g*8 ..+8]
    short8 qf[2];
#pragma unroll
    for (int kb = 0; kb < 2; ++kb)
        qf[kb] = *(const short8*)(Qb + (size_t)(q0 + w * 16 + li) * DH + kb * 32 + g * 8);

    // O^T accumulators: col=q(li), row=dh=16n+4g+rr
    f32x4 Oacc[4] = {};
    float mrun = NEG_INF, lrun = 0.f;

    auto stageK = [&](int bb, int kv) {
#pragma unroll
        for (int i = 0; i < 2; ++i) {
            int o = i * 4096 + w * 1024 + lane * 16;
            int key = o >> 7, slot = (o & 127) >> 4;
            __builtin_amdgcn_global_load_lds(
                AS1C(Kb + (size_t)(kv + key) * DH + ((slot ^ (key & 7)) << 3)),
                AS3(sK + bb * 8192 + i * 4096 + w * 1024), 16, 0, 0);
        }
    };
    auto stageV = [&](int bb, int kv) {
#pragma unroll
        for (int i = 0; i < 2; ++i) {
            int o = i * 4096 + w * 1024 + lane * 16;
            int dh = o >> 7, slot = (o & 127) >> 4;
            __builtin_amdgcn_global_load_lds(
                AS1C(Vb + (size_t)dh * SEQ + kv + ((slot ^ (dh & 7)) << 3)),
                AS3(sVT + bb * 8192 + i * 4096 + w * 1024), 16, 0, 0);
        }
    };

    stageK(0, 0); stageV(0, 0);
    asm volatile("s_waitcnt vmcnt(0)" ::: "memory");
    __syncthreads();

    int cur = 0;
    for (int kv0 = 0; kv0 < loop_end; kv0 += 64) {
        int nxt = kv0 + 64;
        if (nxt < loop_end) { stageK(cur ^ 1, nxt); stageV(cur ^ 1, nxt); }

        // ---- QK^T swapped: S^T[key][q] = mfma(A=K, B=Q), exp2 domain ----
        f32x4 S[4] = {};
        __builtin_amdgcn_s_setprio(1);
#pragma unroll
        for (int kb = 0; kb < 2; ++kb) {
            short8 kf[4];
#pragma unroll
            for (int n = 0; n < 4; ++n) {
                int key = 16 * n + li;
                kf[n] = *(const short8*)(sK + cur * 8192 + key * 128 +
                                         (((4 * kb + g) ^ (key & 7)) << 4));
            }
#pragma unroll
            for (int n = 0; n < 4; ++n)
                S[n] = __builtin_amdgcn_mfma_f32_16x16x32_bf16(kf[n], qf[kb], S[n], 0, 0, 0);
        }
        __builtin_amdgcn_s_setprio(0);

        if (kv0 + 64 > thresh) {
            // straddle tile only: key = kv0 + 16n + 4g + rr
            int tr = thresh - kv0 - 4 * g;
#pragma unroll
            for (int n = 0; n < 4; ++n)
#pragma unroll
                for (int rr = 0; rr < 4; ++rr)
                    if (16 * n + rr >= tr) S[n][rr] = MASKB2;
        }

        // per-lane row max (lane owns q=li)
        float mx = S[0][0];
#pragma unroll
        for (int n = 0; n < 4; ++n)
#pragma unroll
            for (int rr = 0; rr < 4; ++rr) mx = fmaxf(mx, S[n][rr]);
        mx = fmaxf(mx, __shfl_xor(mx, 16));
        mx = fmaxf(mx, __shfl_xor(mx, 32));
        float pmax = mx;

        // defer-max (T13)
        if (__any(pmax > mrun + DEFER_THR)) {
            float mn = fmaxf(mrun, pmax);
            float alpha = fexp2(mrun - mn);
            lrun *= alpha;
#pragma unroll
            for (int n = 0; n < 4; ++n)
#pragma unroll
                for (int rr = 0; rr < 4; ++rr) Oacc[n][rr] *= alpha;
            mrun = mn;
        }

        // exp2 + rowsum + pack directly into PV B-fragments (in-lane, shuffle-free)
        short4v pb[4];
        float rs = 0.f;
#pragma unroll
        for (int n = 0; n < 4; ++n) {
#pragma unroll
            for (int rr = 0; rr < 4; ++rr) {
                float p = fexp2(S[n][rr] - mrun);
                S[n][rr] = p;
                rs += p;
            }
            PB u;
            u.u[0] = pk2(S[n][0], S[n][1]);
            u.u[1] = pk2(S[n][2], S[n][3]);
            pb[n] = u.s4;
        }
        rs += __shfl_xor(rs, 16);
        rs += __shfl_xor(rs, 32);
        lrun += rs;

        // ---- PV: O^T[dh][q] += mfma16x16x16(A=V^T, B=P^T) over 4 k-steps ----
        __builtin_amdgcn_s_setprio(1);
#pragma unroll
        for (int ks = 0; ks < 4; ++ks) {
            int slot = 2 * ks + (g >> 1);
            int sub8 = 8 * (g & 1);
#pragma unroll
            for (int n = 0; n < 4; ++n) {
                int dh = 16 * n + li;
                short4v va = *(const short4v*)(sVT + cur * 8192 + dh * 128 +
                                               ((slot ^ (dh & 7)) << 4) + sub8);
                Oacc[n] = __builtin_amdgcn_mfma_f32_16x16x16bf16_1k(va, pb[ks], Oacc[n], 0, 0, 0);
            }
        }
        __builtin_amdgcn_s_setprio(0);

        asm volatile("s_waitcnt vmcnt(0)" ::: "memory");
        __syncthreads();
        cur ^= 1;
    }

    // ---- analytic masked tail: keys in [loop_end, SEQ) all have score MASKB2 ----
    int nmask = SEQ - loop_end;
    if (nmask > 0) {
        const float* vs = Vsum + bh * DH;
        f32x4 vsf[4];
#pragma unroll
        for (int n = 0; n < 4; ++n) vsf[n] = *(const f32x4*)(vs + 16 * n + 4 * g);
        float pu = fexp2(MASKB2 - mrun);   // mrun >= MASKB2 always
        lrun += (float)nmask * pu;
#pragma unroll
        for (int n = 0; n < 4; ++n)
#pragma unroll
            for (int rr = 0; rr < 4; ++rr) Oacc[n][rr] += pu * vsf[n][rr];
    }

    // ---- epilogue: normalize, write bf16 (8B stores) ----
    float linv = 1.0f / lrun;
    int q = q0 + w * 16 + li;
#pragma unroll
    for (int n = 0; n < 4; ++n) {
        __hip_bfloat16 o4[4];
#pragma unroll
        for (int rr = 0; rr < 4; ++rr) o4[rr] = __float2bfloat16(Oacc[n][rr] * linv);
        *(short4*)(AO + (size_t)(b * SEQ + q) * D_MODEL + h * DH + 16 * n + 4 * g) =
            *(short4*)o4;
    }
}

extern "C" void kernel_launch(void* const* d_in, const int* in_sizes, int n_in,
                              void* d_out, int out_size, void* d_ws, size_t ws_size,
                              hipStream_t stream) {
    const float* queries    = (const float*)d_in[0];
    const float* keys       = (const float*)d_in[1];
    const float* values     = (const float*)d_in[2];
    const int*   thresholds = (const int*)d_in[3];
    const float* Wq = (const float*)d_in[4];
    const float* bq = (const float*)d_in[5];
    const float* Wk = (const float*)d_in[6];
    const float* bk = (const float*)d_in[7];
    const float* Wv = (const float*)d_in[8];
    const float* bv = (const float*)d_in[9];
    const float* W  = (const float*)d_in[10];
    const float* Wo = (const float*)d_in[11];
    const float* bo = (const float*)d_in[12];
    float* out = (float*)d_out;

    char* wsb = (char*)d_ws;
    float* bq2  = (float*)wsb;                         // 4 KB
    float* Vsum = (float*)(wsb + 4096);                // 8 KB
    __hip_bfloat16* XqB = (__hip_bfloat16*)(wsb + 16384);
    __hip_bfloat16* XkB = XqB + (1 << 22);
    __hip_bfloat16* XvB = XkB + (1 << 22);
    __hip_bfloat16* WqT = XvB + (1 << 22);
    __hip_bfloat16* WkT = WqT + (1 << 20);
    __hip_bfloat16* WvT = WkT + (1 << 20);
    __hip_bfloat16* WoT = WvT + (1 << 20);
    __hip_bfloat16* QpB = WoT + (1 << 20);
    __hip_bfloat16* KpB = QpB + (1 << 22);
    __hip_bfloat16* VtB = KpB + (1 << 22);
    __hip_bfloat16* AOB = XqB;   // alias: XqB dead after Q projection

    fold_q_kernel<<<dim3(32, 33), 256, 0, stream>>>(Wq, bq, W, WqT, bq2);
    prep_kernel<<<9216, 256, 0, stream>>>(Wk, Wv, Wo, WkT, WvT, WoT,
                                          queries, keys, values, XqB, XkB, XvB);

    gemm_qkv_kernel<<<dim3(8, 32, 3), 256, 0, stream>>>(XqB, XkB, XvB, WqT, WkT, WvT,
                                                        bq2, bk, bv, QpB, KpB, VtB);
    vsum_kernel<<<32, 256, 0, stream>>>(VtB, thresholds, Vsum);

    attn_mfma_kernel<<<dim3(32, 32), 256, 0, stream>>>(QpB, KpB, VtB, thresholds, Vsum, AOB);

    gemm_out_kernel<<<dim3(8, 32), 256, 0, stream>>>(AOB, WoT, bo, out);
}